// Round 1
// 320.083 us; speedup vs baseline: 1.0992x; 1.0992x over previous
//
#include <hip/hip_runtime.h>

typedef _Float16 half_t;
typedef __attribute__((ext_vector_type(8))) _Float16 half8;
typedef __attribute__((ext_vector_type(4))) _Float16 half4;
typedef __attribute__((ext_vector_type(4))) float float4_t;

#define BN_EPS 1e-5f

constexpr int Nn = 64, Cc = 64, Tt = 300, Vv = 25, Ss = 3;
constexpr int TB   = 4;              // timesteps per block (300/4 = 75, exact -> no t guards)
constexpr int TWN  = TB * Vv;        // 100 = stage-2 N dimension
constexpr int NT   = 7;              // 7 n-tiles of 16 cover 112 >= 100
constexpr int XL_T = 32;             // v-stride (padded 25->32, pads are ZERO = free K-pad)
constexpr int XL_C = TB * XL_T + 8;  // 136 halfs per c row (272 B = 68 dwords ≡ 4 mod 32 banks)
constexpr int XA_S = 72;             // c-stride of xa rows (144 B = 36 dwords ≡ 4 mod 32 banks)
constexpr int XA_R = NT * 16;        // 112 rows
constexpr int AE_S = 40;             // v-stride of transient AeT rows (80 B, 16B-aligned)

__global__ __launch_bounds__(256, 4)
void gcn_fused(const float* __restrict__ x,   const float* __restrict__ A,
               const float* __restrict__ PA1, const float* __restrict__ PA2,
               const float* __restrict__ Wc,  const float* __restrict__ bc,
               const float* __restrict__ gamma, const float* __restrict__ beta,
               const float* __restrict__ rmean, const float* __restrict__ rvar,
               float* __restrict__ out)
{
    __shared__ __align__(16) half_t Xl[Cc * XL_C];       // 17408 B
    __shared__ __align__(16) half_t xaL[XA_R * XA_S];    // 16128 B
    __shared__ float bnsc[Cc], bnsh[Cc];                 // 512 B   (total ~34 KB -> 4 blocks/CU)

    // AeT is staged TRANSIENTLY into the xaL region (3*32*40 = 3840 halfs <= first 7680 B),
    // consumed into registers before stage-1 ever writes xaL.
    half_t* AeU = xaL;

    const int tid  = threadIdx.x;
    const int lane = tid & 63;
    const int wave = tid >> 6;      // 0..3
    const int col  = lane & 15;     // MFMA n/m lane index
    const int quad = lane >> 4;     // 0..3

    const int tb = blockIdx.x;      // 0..74
    const int n  = blockIdx.y;      // 0..63
    const int t0 = tb * TB;

    // ---- BN scale/shift with Sum_s bc[s] folded in ----
    if (tid < Cc) {
        float sc   = gamma[tid] * rsqrtf(rvar[tid] + BN_EPS);
        float bsum = bc[tid] + bc[Cc + tid] + bc[2 * Cc + tid];
        bnsc[tid] = sc;
        bnsh[tid] = beta[tid] - rmean[tid] * sc + bsum * sc;
    }

    // ---- adaptive adjacency, transposed, into the transient AeU region ----
    for (int e = tid; e < Ss * 32 * 32; e += 256) {
        int s = e >> 10, r = e & 1023, w = r >> 5, v = r & 31;
        float val = 0.f;
        if (v < Vv && w < Vv) {
            int ai = (s * Vv + v) * Vv + w;
            val = A[ai] * PA1[ai] + PA2[ai];
        }
        AeU[(s * 32 + w) * AE_S + v] = (half_t)val;
    }

    // ---- zero the xa tail rows 100..111 (halfs 7200.. : disjoint from AeU's 0..3839) ----
    for (int e = tid; e < (XA_R - TWN) * XA_S; e += 256)
        xaL[TWN * XA_S + e] = (half_t)0.f;

    // ---- zero the Xl v-pads (v = 25..31 for each (c,t)) ----
    for (int e = tid; e < Cc * TB * 7; e += 256) {
        int c = e / 28, r = e % 28, t = r / 7, v = 25 + r % 7;
        Xl[c * XL_C + t * XL_T + v] = (half_t)0.f;
    }

    // ---- Wc A-fragments (this wave's o-tile), float4 loads, fp32 -> fp16, in registers ----
    half8 wf[Ss][2];
    {
        int o = wave * 16 + col;                 // A-frag: m = lane&15
        #pragma unroll
        for (int s = 0; s < Ss; ++s)
            #pragma unroll
            for (int ks = 0; ks < 2; ++ks) {
                const float* p = Wc + (s * Cc + o) * Cc + ks * 32 + quad * 8; // k = quad*8+j
                float4_t a = *(const float4_t*)p;
                float4_t b = *(const float4_t*)(p + 4);
                half8 h;
                #pragma unroll
                for (int j = 0; j < 4; ++j) { h[j] = (half_t)a[j]; h[4 + j] = (half_t)b[j]; }
                wf[s][ks] = h;
            }
    }

    // ---- stage x slice into LDS: float4 global loads (100 contiguous floats per c-row),
    //      de-interleave into padded [c][t*32+v] fp16 layout ----
    {
        const float* xb = x + (size_t)n * Cc * Tt * Vv + t0 * Vv;
        for (int i = tid; i < Cc * (TWN / 4); i += 256) {     // 1600 float4s
            int c = i / 25, k = i - c * 25;
            float4_t f = *(const float4_t*)(xb + c * (Tt * Vv) + k * 4);  // 16B-aligned
            int p = k * 4;
            #pragma unroll
            for (int j = 0; j < 4; ++j) {
                int g = p + j;
                int t = g / 25, v = g - t * 25;
                Xl[c * XL_C + t * XL_T + v] = (half_t)f[j];
            }
        }
    }
    __syncthreads();

    // ---- Ae B-frags for ALL s into registers, then the AeU region is dead ----
    half8 ab[Ss][2];
    #pragma unroll
    for (int s = 0; s < Ss; ++s)
        #pragma unroll
        for (int wt = 0; wt < 2; ++wt)
            ab[s][wt] = *(const half8*)&AeU[(s * 32 + wt * 16 + col) * AE_S + quad * 8];
    __syncthreads();   // all waves done reading AeU before stage-1 overwrites xaL

    const float4_t zero4 = {0.f, 0.f, 0.f, 0.f};
    float4_t yacc[NT];
    #pragma unroll
    for (int i = 0; i < NT; ++i) yacc[i] = zero4;

    const int t = wave;   // each wave owns one timestep of the 4

    #pragma unroll
    for (int s = 0; s < Ss; ++s) {
        // ---- stage 1: xa[c][(t,w)] = X · Ae[s], K=32 covers v=25 (zero-padded) ----
        #pragma unroll
        for (int ct = 0; ct < 4; ++ct) {
            // A-frag: m = c = ct*16+col, k = v = quad*8+j
            half8 af = *(const half8*)&Xl[(ct * 16 + col) * XL_C + t * XL_T + quad * 8];
            #pragma unroll
            for (int wt = 0; wt < 2; ++wt) {
                float4_t r = __builtin_amdgcn_mfma_f32_16x16x32_f16(af, ab[s][wt], zero4, 0, 0, 0);
                int w = wt * 16 + col;           // C/D: col = lane&15
                if (w < Vv) {
                    half4 h;
                    #pragma unroll
                    for (int i2 = 0; i2 < 4; ++i2) h[i2] = (half_t)r[i2]; // rows = quad*4+i = consecutive c
                    *(half4*)&xaL[(t * Vv + w) * XA_S + ct * 16 + quad * 4] = h;
                }
            }
        }
        __syncthreads();

        // ---- stage 2: y[o][(t,w)] += Wc[s] · xa  (M=64 over waves, N=112, K=64) ----
        #pragma unroll
        for (int nt = 0; nt < NT; ++nt) {
            int tw = nt * 16 + col;              // B-frag: n = tw
            #pragma unroll
            for (int ks = 0; ks < 2; ++ks) {
                half8 bf = *(const half8*)&xaL[tw * XA_S + ks * 32 + quad * 8]; // k = c
                yacc[nt] = __builtin_amdgcn_mfma_f32_16x16x32_f16(wf[s][ks], bf, yacc[nt], 0, 0, 0);
            }
        }
        if (s != Ss - 1) __syncthreads();        // xaL rewritten next s
    }

    // ---- epilogue: BN + residual (from Xl) + ReLU, coalesced stores ----
    float* ob = out + (size_t)n * Cc * Tt * Vv + t0 * Vv;
    #pragma unroll
    for (int nt = 0; nt < NT; ++nt) {
        int tw = nt * 16 + col;
        if (tw < TWN) {
            int tt = tw / 25;
            int w  = tw - tt * 25;
            #pragma unroll
            for (int i = 0; i < 4; ++i) {
                int o = wave * 16 + quad * 4 + i;
                float val = yacc[nt][i] * bnsc[o] + bnsh[o];
                val += (float)Xl[o * XL_C + tt * XL_T + w];   // residual
                ob[o * Tt * Vv + tw] = fmaxf(val, 0.f);       // contiguous in tw
            }
        }
    }
}

extern "C" void kernel_launch(void* const* d_in, const int* in_sizes, int n_in,
                              void* d_out, int out_size, void* d_ws, size_t ws_size,
                              hipStream_t stream) {
    const float* x     = (const float*)d_in[0];
    const float* A     = (const float*)d_in[1];
    const float* PA1   = (const float*)d_in[2];
    const float* PA2   = (const float*)d_in[3];
    const float* Wc    = (const float*)d_in[4];
    const float* bc    = (const float*)d_in[5];
    const float* gamma = (const float*)d_in[6];
    const float* beta  = (const float*)d_in[7];
    const float* rmean = (const float*)d_in[8];
    const float* rvar  = (const float*)d_in[9];
    float* out = (float*)d_out;

    dim3 grid(Tt / TB, Nn);   // (75, 64)
    gcn_fused<<<grid, 256, 0, stream>>>(x, A, PA1, PA2, Wc, bc, gamma, beta, rmean, rvar, out);
}